// Round 5
// baseline (272.982 us; speedup 1.0000x reference)
//
#include <hip/hip_runtime.h>
#include <stdint.h>

typedef __attribute__((ext_vector_type(8))) unsigned short ushort8;
typedef __attribute__((ext_vector_type(8))) __bf16 bf16x8;
typedef __attribute__((ext_vector_type(4))) float f32x4;
typedef __attribute__((ext_vector_type(4))) uint32_t u32x4;

__device__ __forceinline__ unsigned short f2bf(float f) {
  union { float f; uint32_t u; } x; x.f = f;
  uint32_t u = x.u;
  uint32_t r = (u + 0x7fffu + ((u >> 16) & 1u)) >> 16;
  return (unsigned short)r;
}

__device__ __forceinline__ uint32_t pack_bf2(float lo, float hi) {
  return (uint32_t)f2bf(lo) | ((uint32_t)f2bf(hi) << 16);
}

// round-half-up bf16 pair pack: 2 adds + 1 v_perm (≡ RNE for positive non-ties)
__device__ __forceinline__ uint32_t rhu2(float lo, float hi) {
  union { float f; uint32_t u; } a, b; a.f = lo; b.f = hi;
  return __builtin_amdgcn_perm(b.u + 0x8000u, a.u + 0x8000u, 0x07060302u);
}

__device__ __forceinline__ void store_c(unsigned short* p, float v) { *p = f2bf(v); }
__device__ __forceinline__ void store_c(float* p, float v) { *p = v; }

__device__ __forceinline__ void gll16(const unsigned short* g, unsigned short* l) {
  __builtin_amdgcn_global_load_lds((const __attribute__((address_space(1))) void*)g,
                                   (__attribute__((address_space(3))) void*)l,
                                   16, 0, 0);
}

// ---------------------------------------------------------------------------
// fp32 -> bf16 convert (RNE). One thread = 4 elements.
// ---------------------------------------------------------------------------
__global__ __launch_bounds__(256) void cvt_f32_bf16(
    const float* __restrict__ x, unsigned short* __restrict__ y, int n4) {
  int i = blockIdx.x * 256 + threadIdx.x;
  if (i >= n4) return;
  float4 v = *(const float4*)(x + (size_t)i * 4);
  uint2 p; p.x = pack_bf2(v.x, v.y); p.y = pack_bf2(v.z, v.w);
  *(uint2*)(y + (size_t)i * 4) = p;
}

// ---------------------------------------------------------------------------
// Weight transpose + convert: WT[n][k] = bf16(W[k][n]), 1024x1024 fp32 in.
// Batched x3 (wq/wk/wv) via blockIdx.z; single version kept for wo.
// ---------------------------------------------------------------------------
__device__ __forceinline__ void transpose_body(const float* W, unsigned short* WT) {
  __shared__ unsigned short tile[32][33];
  int c0 = blockIdx.x * 32, r0 = blockIdx.y * 32;
  int x = threadIdx.x, y = threadIdx.y;
#pragma unroll
  for (int i = 0; i < 32; i += 8)
    tile[y + i][x] = f2bf(W[(size_t)(r0 + y + i) * 1024 + c0 + x]);
  __syncthreads();
#pragma unroll
  for (int i = 0; i < 32; i += 8)
    WT[(size_t)(c0 + y + i) * 1024 + r0 + x] = tile[x][y + i];
}

__global__ void transpose_w(const float* __restrict__ W,
                            unsigned short* __restrict__ WT) {
  transpose_body(W, WT);
}

__global__ void transpose_w3(const float* W0, const float* W1, const float* W2,
                             unsigned short* T0, unsigned short* T1,
                             unsigned short* T2) {
  const float* W = (blockIdx.z == 0) ? W0 : (blockIdx.z == 1) ? W1 : W2;
  unsigned short* WT = (blockIdx.z == 0) ? T0 : (blockIdx.z == 1) ? T1 : T2;
  transpose_body(W, WT);
}

// ---------------------------------------------------------------------------
// GEMM R14 (gemm4): C[M,N] = A[M,K]*B[K,N] given BT[N,K], bf16, fp32 accum.
// 128x128 tile, BK=32, 256 thr (4 waves as 2m x 2n, each 64x64 out).
// (a) 3-stage pipeline, 48 KB LDS -> 3 blocks/CU (12 waves/CU):
//       prologue: STAGE(0->buf0), STAGE(1->buf1)
//       iter t:   s_waitcnt vmcnt(4)   // retire STAGE(t); STAGE(t+1) stays
//                                      // in flight (4 gll16 per stage/wave)
//                 s_barrier            // all waves agree buf[t%3] ready
//                 STAGE(t+2 -> buf[(t+2)%3])
//                 ds_read buf[t%3], 16 MFMA
//     No vmcnt(0) in the loop (T4). Race-free with ONE barrier because the
//     write target buf[(t+2)%3] was last read in iter t-1, and those ds_reads
//     retired (operand-consumed) before that wave entered barrier(t).
// (b) XCD-chunked A-panel-major remap: my = (orig&7)*(total/8) + orig>>3;
//     bx = my/nsub, sub = my%nsub, z = sub/nby, by = sub%nby. Each XCD gets
//     a contiguous run of A-panels (2 MB, L2-resident) x all (by,z) -> A is
//     fetched ~once per XCD instead of ~24x from L3. Bijective: total%8==0.
// Both-sides XOR swizzle (chunk' = chunk ^ (row&3)): gll16 dest linear,
// source col pre-swizzled (lane-constant on read: fq ^ (fr&3)).
// sc0: epilogue scale when z==0 (folds attn head_scale*log2e into q proj).
// ---------------------------------------------------------------------------
template <typename OutT>
__global__ __launch_bounds__(256, 3) void gemm4(
    const unsigned short* A,
    const unsigned short* BT0, const unsigned short* BT1, const unsigned short* BT2,
    OutT* C0, OutT* C1, OutT* C2,
    int M, int N, int K, float sc0, int nby) {
  // ---- block remap ----
  const int total = gridDim.x * gridDim.y;
  const int orig = blockIdx.y * gridDim.x + blockIdx.x;
  const int per8 = total >> 3;
  const int my = (orig & 7) * per8 + (orig >> 3);
  const int nsub = gridDim.x;  // 3*nby (QKV) or nby (final)
  const int bxi = my / nsub;
  const int sub = my - bxi * nsub;
  const int z = sub / nby;
  const int byi = sub - z * nby;

  const unsigned short* BT = (z == 0) ? BT0 : (z == 1) ? BT1 : BT2;
  OutT* C = (z == 0) ? C0 : (z == 1) ? C1 : C2;
  const float sc = (z == 0) ? sc0 : 1.0f;

  __shared__ __attribute__((aligned(16))) unsigned short As[3][128 * 32];
  __shared__ __attribute__((aligned(16))) unsigned short Bs[3][128 * 32];

  const int tid = threadIdx.x;
  const int wave = tid >> 6, lane = tid & 63;
  const int fr = lane & 15, fq = lane >> 4;
  const int wm = wave >> 1, wn = wave & 1;
  const int bm = bxi * 128, bn = byi * 128;

  // staging: per wave per stage, 2 gll16 for A + 2 for B (1 KB each:
  // 16 rows x 64 B). lane covers (row = i*64 + wave*16 + (lane>>2),
  // chunk = lane&3); source chunk pre-swizzled by row&3 = (lane>>2)&3
  // (instruction-invariant since i*64, wave*16 are multiples of 4).
  const int r4 = lane >> 2, c4 = lane & 3;
  const int scs = (c4 ^ (r4 & 3)) * 8;
  const unsigned short* Ag = A + (size_t)(bm + wave * 16 + r4) * K + scs;
  const unsigned short* Bg = BT + (size_t)(bn + wave * 16 + r4) * K + scs;

  f32x4 acc[4][4] = {};
  const int NT = K >> 5;

  auto STAGE = [&](int buf, int t) {
    const size_t k0 = (size_t)t * 32;
    gll16(Ag + k0, &As[buf][(wave * 16) * 32]);
    gll16(Ag + k0 + (size_t)64 * K, &As[buf][(64 + wave * 16) * 32]);
    gll16(Bg + k0, &Bs[buf][(wave * 16) * 32]);
    gll16(Bg + k0 + (size_t)64 * K, &Bs[buf][(64 + wave * 16) * 32]);
  };

  // read-side swizzle: row = wm*64 + mt*16 + fr -> row&3 = fr&3 (const)
  const int rxr = (fq ^ (fr & 3)) * 8;

  STAGE(0, 0);
  STAGE(1, 1);

  int bc = 0, bs = 2;
  for (int t = 0; t < NT; ++t) {
    if (t + 1 < NT)
      asm volatile("s_waitcnt vmcnt(4)" ::: "memory");
    else
      asm volatile("s_waitcnt vmcnt(0)" ::: "memory");
    __builtin_amdgcn_s_barrier();

    if (t + 2 < NT) STAGE(bs, t + 2);

    bf16x8 af[4], bfr[4];
#pragma unroll
    for (int mt = 0; mt < 4; mt++)
      af[mt] = *(const bf16x8*)&As[bc][(wm * 64 + mt * 16 + fr) * 32 + rxr];
#pragma unroll
    for (int nt = 0; nt < 4; nt++)
      bfr[nt] = *(const bf16x8*)&Bs[bc][(wn * 64 + nt * 16 + fr) * 32 + rxr];
#pragma unroll
    for (int mt = 0; mt < 4; mt++)
#pragma unroll
      for (int nt = 0; nt < 4; nt++)
        acc[mt][nt] = __builtin_amdgcn_mfma_f32_16x16x32_bf16(af[mt], bfr[nt], acc[mt][nt], 0, 0, 0);

    bc = (bc == 2) ? 0 : bc + 1;
    bs = (bs == 2) ? 0 : bs + 1;
  }

#pragma unroll
  for (int mt = 0; mt < 4; mt++)
#pragma unroll
    for (int nt = 0; nt < 4; nt++)
#pragma unroll
      for (int r = 0; r < 4; r++) {
        int row = bm + wm * 64 + mt * 16 + fq * 4 + r;
        int col = bn + wn * 64 + nt * 16 + fr;
        store_c(&C[(size_t)row * N + col], acc[mt][nt][r] * sc);
      }
}

// ---------------------------------------------------------------------------
// Flash attention R11 (unchanged): XOR-swizzled zero-conflict LDS, K double-
// buffered via global_load_lds prefetch issued after barrier B, V staged
// single-buffered with short reg live range, q pre-scaled, setprio on MFMA.
// ---------------------------------------------------------------------------
__global__ __launch_bounds__(256, 4) void attn_kernel(
    const unsigned short* q, const unsigned short* k,
    const unsigned short* v, unsigned short* o) {
  const int S = 2048, E = 1024;
  __shared__ __attribute__((aligned(16))) unsigned short Ksb[2 * 64 * 64];
  __shared__ __attribute__((aligned(16))) unsigned short Vtb[64 * 64];

  const int tid = threadIdx.x;
  const int wave = tid >> 6, lane = tid & 63;
  const int fr = lane & 15, fq = lane >> 4;
  const int q0 = blockIdx.x * 128;
  const int bh = blockIdx.y;
  const int b = bh >> 4, h = bh & 15;
  const size_t base = ((size_t)b * S) * E + (size_t)h * 64;

  bf16x8 aq[2][2];
#pragma unroll
  for (int qg = 0; qg < 2; qg++)
#pragma unroll
    for (int ks = 0; ks < 2; ks++)
      aq[qg][ks] = *(const bf16x8*)&q[base +
          (size_t)(q0 + qg * 64 + wave * 16 + fr) * E + ks * 32 + fq * 8];

  ushort8 ones_u;
#pragma unroll
  for (int j = 0; j < 8; j++) ones_u[j] = 0x3F80;  // bf16 1.0
  bf16x8 onesf = *(bf16x8*)&ones_u;

  f32x4 ot[2][4] = {};
  f32x4 osum[2] = {};

  const int srow = lane >> 3;
  const int scol = (((lane & 7) ^ srow) << 3);
  const unsigned short* Kg = k + base + (size_t)(wave * 16 + srow) * E + scol;

  const int rp = (tid & 31) * 2;
  const int dcv = (tid >> 5) * 8;
  const int u_ = rp & 31;
  const int slot = 32 * (rp >> 5) + 8 * ((u_ & 15) >> 2) + 4 * (u_ >> 4) + (u_ & 3);
  const unsigned short* Vg = v + base + (size_t)rp * E + dcv;

  const int rx = (fr & 7) << 3;

  gll16(Kg, &Ksb[wave * 1024]);
  gll16(Kg + 8 * (size_t)E, &Ksb[wave * 1024 + 512]);

  int cur = 0;
  for (int t = 0; t < 32; t++) {
    const int nxt = cur ^ 4096;

    const size_t toff = (size_t)t * 64 * E;
    u32x4 va = *(const u32x4*)(Vg + toff);
    u32x4 vb = *(const u32x4*)(Vg + toff + E);

    __syncthreads();  // A: drains K[t] (prefetched a phase ago) + va/vb

#pragma unroll
    for (int w = 0; w < 4; w++) {
      uint32_t lo = __builtin_amdgcn_perm(vb[w], va[w], 0x05040100u);
      uint32_t hi = __builtin_amdgcn_perm(vb[w], va[w], 0x07060302u);
      int d = dcv + 2 * w;
      *(uint32_t*)&Vtb[d * 64 + (slot ^ ((2 * w) << 3))] = lo;
      *(uint32_t*)&Vtb[(d + 1) * 64 + (slot ^ ((2 * w + 1) << 3))] = hi;
    }

    __syncthreads();  // B: staged data visible

    if (t < 31) {
      const size_t poff = (size_t)(t + 1) * 64 * E;
      gll16(Kg + poff, &Ksb[nxt + wave * 1024]);
      gll16(Kg + poff + 8 * (size_t)E, &Ksb[nxt + wave * 1024 + 512]);
    }

    f32x4 st[2][4] = {};
    __builtin_amdgcn_s_setprio(1);
#pragma unroll
    for (int ks = 0; ks < 2; ks++) {
#pragma unroll
      for (int tt = 0; tt < 4; tt++) {
        bf16x8 ak = *(const bf16x8*)&Ksb[cur + (tt * 16 + fr) * 64 +
                                         ((ks * 32 + fq * 8) ^ rx)];
        st[0][tt] = __builtin_amdgcn_mfma_f32_16x16x32_bf16(ak, aq[0][ks], st[0][tt], 0, 0, 0);
        st[1][tt] = __builtin_amdgcn_mfma_f32_16x16x32_bf16(ak, aq[1][ks], st[1][tt], 0, 0, 0);
      }
    }
    __builtin_amdgcn_s_setprio(0);

    uint32_t pk[2][4][2];
#pragma unroll
    for (int qg = 0; qg < 2; qg++)
#pragma unroll
      for (int tt = 0; tt < 4; tt++) {
        float e0 = __builtin_amdgcn_exp2f(st[qg][tt][0]);
        float e1 = __builtin_amdgcn_exp2f(st[qg][tt][1]);
        float e2 = __builtin_amdgcn_exp2f(st[qg][tt][2]);
        float e3 = __builtin_amdgcn_exp2f(st[qg][tt][3]);
        pk[qg][tt][0] = rhu2(e0, e1);
        pk[qg][tt][1] = rhu2(e2, e3);
      }

    __builtin_amdgcn_s_setprio(1);
#pragma unroll
    for (int c = 0; c < 2; c++) {
      bf16x8 bp[2];
#pragma unroll
      for (int qg = 0; qg < 2; qg++) {
        u32x4 bpr;
        bpr[0] = pk[qg][2 * c][0];
        bpr[1] = pk[qg][2 * c][1];
        bpr[2] = pk[qg][2 * c + 1][0];
        bpr[3] = pk[qg][2 * c + 1][1];
        bp[qg] = *(bf16x8*)&bpr;
      }
#pragma unroll
      for (int dt = 0; dt < 4; dt++) {
        bf16x8 av = *(const bf16x8*)&Vtb[(dt * 16 + fr) * 64 +
                                         ((c * 32 + fq * 8) ^ rx)];
        ot[0][dt] = __builtin_amdgcn_mfma_f32_16x16x32_bf16(av, bp[0], ot[0][dt], 0, 0, 0);
        ot[1][dt] = __builtin_amdgcn_mfma_f32_16x16x32_bf16(av, bp[1], ot[1][dt], 0, 0, 0);
      }
      osum[0] = __builtin_amdgcn_mfma_f32_16x16x32_bf16(onesf, bp[0], osum[0], 0, 0, 0);
      osum[1] = __builtin_amdgcn_mfma_f32_16x16x32_bf16(onesf, bp[1], osum[1], 0, 0, 0);
    }
    __builtin_amdgcn_s_setprio(0);

    cur = nxt;
  }

#pragma unroll
  for (int qg = 0; qg < 2; qg++) {
    float inv = 1.0f / osum[qg][0];
    size_t rowbase = base + (size_t)(q0 + qg * 64 + wave * 16 + fr) * E;
#pragma unroll
    for (int dt = 0; dt < 4; dt++) {
      uint32_t w0 = rhu2(ot[qg][dt][0] * inv, ot[qg][dt][1] * inv);
      uint32_t w1 = rhu2(ot[qg][dt][2] * inv, ot[qg][dt][3] * inv);
      *(uint32_t*)&o[rowbase + dt * 16 + fq * 4] = w0;
      *(uint32_t*)&o[rowbase + dt * 16 + fq * 4 + 2] = w1;
    }
  }
}

// ---------------------------------------------------------------------------
// ws: 3 x 1M (weights) + 3 x 8M (q/k/v) shorts = 54 MB.
// bf16 hidden_states lives in d_out's first 16 MB (dead before final GEMM).
// woT reuses wqT's slot (transposed only after the QKV GEMM has consumed
// wqT). Final GEMM writes fp32 to d_out.
// ---------------------------------------------------------------------------
extern "C" void kernel_launch(void* const* d_in, const int* in_sizes, int n_in,
                              void* d_out, int out_size, void* d_ws, size_t ws_size,
                              hipStream_t stream) {
  const float* hs = (const float*)d_in[0];
  const float* wq = (const float*)d_in[1];
  const float* wk = (const float*)d_in[2];
  const float* wv = (const float*)d_in[3];
  const float* wo = (const float*)d_in[4];
  unsigned short* ws = (unsigned short*)d_ws;

  unsigned short* wqT = ws;
  unsigned short* wkT = ws + 1048576;
  unsigned short* wvT = ws + 2097152;
  unsigned short* woT = wqT;
  unsigned short* qb  = ws + 3145728;
  unsigned short* kb  = qb + 8388608;
  unsigned short* vb  = kb + 8388608;
  unsigned short* ob  = qb;
  unsigned short* hsb = (unsigned short*)d_out;
  float* out = (float*)d_out;

  const int M = 8192, N = 1024, K = 1024;
  const float KSC = 0.125f * 1.44269504088896341f;  // head_scale * log2(e)

  cvt_f32_bf16<<<dim3(M * K / 4 / 256), 256, 0, stream>>>(hs, hsb, M * K / 4);

  dim3 tb(32, 8);
  transpose_w3<<<dim3(32, 32, 3), tb, 0, stream>>>(wq, wk, wv, wqT, wkT, wvT);

  // grid.x = (z,by) = 24, grid.y = bx = 64 -> 1536 blocks (1536 % 8 == 0)
  gemm4<unsigned short><<<dim3(24, 64), 256, 0, stream>>>(
      hsb, wqT, wkT, wvT, qb, kb, vb, M, N, K, KSC, 8);

  transpose_w<<<dim3(32, 32), tb, 0, stream>>>(wo, woT);

  attn_kernel<<<dim3(2048 / 128, 64), 256, 0, stream>>>(qb, kb, vb, ob);

  // grid.x = by = 8, grid.y = bx = 64 -> 512 blocks (512 % 8 == 0)
  gemm4<float><<<dim3(8, 64), 256, 0, stream>>>(
      ob, woT, woT, woT, out, out, out, M, N, K, 1.0f, 8);
}